// Round 8
// baseline (210.670 us; speedup 1.0000x reference)
//
#include <hip/hip_runtime.h>

#define T_DIM 720
#define B_DIM 50000

#define OFF_SEAS (T_DIM * B_DIM)                  /* 36,000,000 */
#define SEAS_ROWS 727
#define OFF_MSLD (OFF_SEAS + SEAS_ROWS * B_DIM)   /* 72,350,000 */
#define N_MSLD 718

#define NBLK 1563                                 /* ceil(50000/32) 32-lane waves */
#define NW NBLK

// Sum over lanes 0..31 via DPP (row_shr 1/2/4/8 + row_bcast:15).
// Result lands in lane 31. old=0 is the add identity for out-of-range reads.
__device__ __forceinline__ float dpp_sum32(float v) {
#define DPP_ADD_STAGE(CTRL, RMASK)                                             \
  v += __int_as_float(__builtin_amdgcn_update_dpp(0, __float_as_int(v),        \
                                                  CTRL, RMASK, 0xf, false));
  DPP_ADD_STAGE(0x111, 0xf)  // row_shr:1
  DPP_ADD_STAGE(0x112, 0xf)  // row_shr:2
  DPP_ADD_STAGE(0x114, 0xf)  // row_shr:4
  DPP_ADD_STAGE(0x118, 0xf)  // row_shr:8
  DPP_ADD_STAGE(0x142, 0xa)  // row_bcast:15 -> row 1: lane31 = lanes 0..31
#undef DPP_ADD_STAGE
  return v;
}

// One recurrence step, compute only (reduction batched at group end).
// Output stores: uniform SGPR base + shared 32-bit byte offset (saddr form).
#define ESRNN_STEP(QB, POS)                                                    \
  {                                                                            \
    float x = QB[POS];                                                         \
    float s = buf[POS];                                                        \
    float nl = fmaf(lsm, __fdividef(x, s), olm * lev);                         \
    float ll = __logf(nl);                                                     \
    float ld = ll - llev;                                                      \
    float ns = fmaf(ssm, __fdividef(x, nl), osm * s);                          \
    buf[POS] = ns;                                                             \
    if (valid) {                                                               \
      *(float*)(lbase + boff) = nl;                                            \
      *(float*)(sbase + boff) = ns;                                            \
    }                                                                          \
    boff += B_DIM * 4;                                                         \
    float d = ld - pld;                                                        \
    sqv[POS] = valid ? d * d : 0.0f;                                           \
    pld = ld;                                                                  \
    llev = ll;                                                                 \
    lev = nl;                                                                  \
  }

// Prefetch group G (rows 1+7G .. 7+7G, clamped) into QB (NT: read-once).
#define PREFETCH(QB, G)                                                        \
  {                                                                            \
    int tp = 1 + 7 * (G);                                                      \
    _Pragma("unroll") for (int j = 0; j < 7; ++j) {                            \
      int r = tp + j;                                                          \
      r = r > 719 ? 719 : r;                                                   \
      QB[j] = __builtin_nontemporal_load(&train[r * B_DIM + bc]);              \
    }                                                                          \
  }

// Batched reduction: 7 independent 5-stage DPP chains (pipelined), then the
// lane-31 stores. tb = t of first step in this group; partial row = tb+j-2.
#define GROUP_REDUCE                                                           \
  {                                                                            \
    _Pragma("unroll") for (int j = 0; j < 7; ++j) sqv[j] = dpp_sum32(sqv[j]);  \
    if (lane == 31) {                                                          \
      _Pragma("unroll") for (int j = 0; j < 7; ++j) {                          \
        int row = tb + j - 2;                                                  \
        if (row >= 0) partial[row * NW + wid] = sqv[j];                        \
      }                                                                        \
    }                                                                          \
  }

#define ESRNN_GROUP(QB, QP)                                                    \
  {                                                                            \
    PREFETCH(QP, g + 2)                                                        \
    int tb = 1 + 7 * g;                                                        \
    ESRNN_STEP(QB, 0)                                                          \
    ESRNN_STEP(QB, 1)                                                          \
    ESRNN_STEP(QB, 2)                                                          \
    ESRNN_STEP(QB, 3)                                                          \
    ESRNN_STEP(QB, 4)                                                          \
    ESRNN_STEP(QB, 5)                                                          \
    ESRNN_STEP(QB, 6)                                                          \
    GROUP_REDUCE                                                               \
    ++g;                                                                       \
  }

__global__ __launch_bounds__(64) void esrnn_main(
    const float* __restrict__ train,        // (720, B)
    const float* __restrict__ lev_sms,      // (B,)
    const float* __restrict__ seas_sms,     // (B,)
    const float* __restrict__ init_seas_in, // (B, 7)
    float* __restrict__ levs_out,           // (720, B)
    float* __restrict__ seas_out,           // (727, B)
    float* __restrict__ partial)            // (718, NW) per-wave partials
{
  int lane = threadIdx.x;                 // 0..63; lanes 32..63 idle
  int b = blockIdx.x * 32 + lane;         // series index (lanes 0..31)
  bool valid = (lane < 32) && (b < B_DIM);
  int bc = valid ? b : (B_DIM - 1);
  int wid = blockIdx.x;

  float lsm = 1.0f / (1.0f + __expf(-lev_sms[bc]));
  float ssm = 1.0f / (1.0f + __expf(-seas_sms[bc]));
  float olm = 1.0f - lsm;
  float osm = 1.0f - ssm;

  float is[7];
#pragma unroll
  for (int j = 0; j < 7; ++j) is[j] = __expf(init_seas_in[bc * 7 + j]);

  float seas0 = is[0];
  float x0 = train[bc];
  float lev = __fdividef(x0, seas0);

  if (valid) {
    levs_out[b] = lev;
#pragma unroll
    for (int j = 0; j < 7; ++j) seas_out[j * B_DIM + b] = is[j];
    seas_out[7 * B_DIM + b] = seas0;
  }

  float buf[7];
#pragma unroll
  for (int j = 0; j < 6; ++j) buf[j] = is[j + 1];
  buf[6] = seas0;

  float llev = __logf(lev);
  float pld = 0.0f;

  // saddr-form store bases (SGPR) + shared per-lane byte offset (VGPR).
  char* lbase = (char*)levs_out + (size_t)B_DIM * 4;      // row t=1
  char* sbase = (char*)seas_out + (size_t)8 * B_DIM * 4;  // row t+7=8
  unsigned int boff = (unsigned int)b * 4u;

  float xa[7], xb[7], xc[7], sqv[7];
  int g = 0;
  PREFETCH(xa, 0)
  PREFETCH(xb, 1)

  // 102 groups = 34 x 3-phase buffer rotation, prefetching 2 groups ahead.
  for (int k = 0; k < 34; ++k) {
    ESRNN_GROUP(xa, xc)
    ESRNN_GROUP(xb, xa)
    ESRNN_GROUP(xc, xb)
  }

  // tail: t = 715..719 in xa (group 102), buf pos 0..4
  {
    int tb = 1 + 7 * g;  // 715
    ESRNN_STEP(xa, 0)
    ESRNN_STEP(xa, 1)
    ESRNN_STEP(xa, 2)
    ESRNN_STEP(xa, 3)
    ESRNN_STEP(xa, 4)
#pragma unroll
    for (int j = 0; j < 5; ++j) sqv[j] = dpp_sum32(sqv[j]);
    if (lane == 31) {
#pragma unroll
      for (int j = 0; j < 5; ++j) partial[(tb + j - 2) * NW + wid] = sqv[j];
    }
  }
}

__global__ __launch_bounds__(64) void esrnn_reduce2(
    const float* __restrict__ partial, float* __restrict__ msld) {
  int row = blockIdx.x;  // 0..717
  int lane = threadIdx.x;
  float s = 0.0f;
  for (int i = lane; i < NW; i += 64) s += partial[row * NW + i];
  // full 64-lane sum: 32-lane tree + row_bcast:31 to fold the two halves
  s = dpp_sum32(s);
  s += __int_as_float(__builtin_amdgcn_update_dpp(0, __float_as_int(s),
                                                  0x143, 0xc, 0xf, false));
  if (lane == 63) msld[row] = s * (1.0f / (float)B_DIM);
}

extern "C" void kernel_launch(void* const* d_in, const int* in_sizes, int n_in,
                              void* d_out, int out_size, void* d_ws,
                              size_t ws_size, hipStream_t stream) {
  const float* train = (const float*)d_in[0];
  const float* lev_sms = (const float*)d_in[1];
  const float* seas_sms = (const float*)d_in[2];
  const float* init_seas = (const float*)d_in[3];

  float* out = (float*)d_out;
  float* levs = out;
  float* seas = out + OFF_SEAS;
  float* msld = out + OFF_MSLD;
  float* partial = (float*)d_ws;  // 718*1563*4 ~= 4.5 MB

  esrnn_main<<<NBLK, 64, 0, stream>>>(train, lev_sms, seas_sms, init_seas,
                                      levs, seas, partial);
  esrnn_reduce2<<<N_MSLD, 64, 0, stream>>>(partial, msld);
}

// Round 9
// 125.507 us; speedup vs baseline: 1.6785x; 1.6785x over previous
//
#include <hip/hip_runtime.h>

#define T_DIM 720
#define B_DIM 50000

#define OFF_SEAS (T_DIM * B_DIM)                  /* 36,000,000 */
#define SEAS_ROWS 727
#define OFF_MSLD (OFF_SEAS + SEAS_ROWS * B_DIM)   /* 72,350,000 */
#define N_MSLD 718

#define NBLK 782                                  /* ceil(50000/64) 1-wave blocks */
#define NW NBLK
#define LN2_SQ 0.4804530139182014f                /* (ln 2)^2 */

// Wave64 sum via DPP: row_shr 1/2/4/8, row_bcast 15/31. Result in lane 63.
__device__ __forceinline__ float dpp_sum64(float v) {
#define DPP_ADD_STAGE(CTRL, RMASK)                                             \
  v += __int_as_float(__builtin_amdgcn_update_dpp(0, __float_as_int(v),        \
                                                  CTRL, RMASK, 0xf, false));
  DPP_ADD_STAGE(0x111, 0xf)  // row_shr:1
  DPP_ADD_STAGE(0x112, 0xf)  // row_shr:2
  DPP_ADD_STAGE(0x114, 0xf)  // row_shr:4
  DPP_ADD_STAGE(0x118, 0xf)  // row_shr:8
  DPP_ADD_STAGE(0x142, 0xa)  // row_bcast:15
  DPP_ADD_STAGE(0x143, 0xc)  // row_bcast:31
#undef DPP_ADD_STAGE
  return v;
}

// Prefetch group G (rows 1+7G .. 7+7G, clamped) into QB (NT: read-once).
#define PREFETCH(QB, G)                                                        \
  {                                                                            \
    int tp = 1 + 7 * (G);                                                      \
    _Pragma("unroll") for (int j = 0; j < 7; ++j) {                            \
      int r = tp + j;                                                          \
      r = r > 719 ? 719 : r;                                                   \
      QB[j] = __builtin_nontemporal_load(&train[r * B_DIM + bc]);              \
    }                                                                          \
  }

// One group, batched into ILP phases. NS = number of steps (7, tail 5).
// Phase 1: 7 independent divides (depend only on prev group's buf).
// Phase 2: the true loop-carried chain — NS chained FMAs.
// Phase 3: NS independent log2's. Phase 4: NS independent divides + buf update.
// Phase 5: coalesced output stores. Phase 6: log2-diff squares.
// Phase 7: NS independent 6-stage DPP trees + lane-63 partial stores.
#define ESRNN_GROUP_N(QB, NS)                                                  \
  {                                                                            \
    float xds[7], nlv[7], llv[7];                                              \
    _Pragma("unroll") for (int j = 0; j < (NS); ++j)                           \
        xds[j] = __fdividef(QB[j], buf[j]);                                    \
    nlv[0] = fmaf(lsm, xds[0], olm * lev);                                     \
    _Pragma("unroll") for (int j = 1; j < (NS); ++j)                           \
        nlv[j] = fmaf(lsm, xds[j], olm * nlv[j - 1]);                          \
    _Pragma("unroll") for (int j = 0; j < (NS); ++j)                           \
        llv[j] = __log2f(nlv[j]);                                              \
    _Pragma("unroll") for (int j = 0; j < (NS); ++j) {                         \
      float ns = fmaf(ssm, __fdividef(QB[j], nlv[j]), osm * buf[j]);           \
      buf[j] = ns;                                                             \
    }                                                                          \
    if (valid) {                                                               \
      _Pragma("unroll") for (int j = 0; j < (NS); ++j) {                       \
        *(float*)(lbase + boff + (unsigned)(j * B_DIM * 4)) = nlv[j];          \
        *(float*)(sbase + boff + (unsigned)(j * B_DIM * 4)) = buf[j];          \
      }                                                                        \
    }                                                                          \
    boff += (NS)*B_DIM * 4;                                                    \
    float sqv[7];                                                              \
    {                                                                          \
      float ld0 = llv[0] - llev;                                               \
      float d0 = ld0 - pld;                                                    \
      sqv[0] = valid ? d0 * d0 : 0.0f;                                         \
      float ldp = ld0;                                                         \
      _Pragma("unroll") for (int j = 1; j < (NS); ++j) {                       \
        float ld = llv[j] - llv[j - 1];                                        \
        float d = ld - ldp;                                                    \
        sqv[j] = valid ? d * d : 0.0f;                                         \
        ldp = ld;                                                              \
      }                                                                        \
      pld = ldp;                                                               \
    }                                                                          \
    llev = llv[(NS)-1];                                                        \
    lev = nlv[(NS)-1];                                                         \
    _Pragma("unroll") for (int j = 0; j < (NS); ++j)                           \
        sqv[j] = dpp_sum64(sqv[j]);                                            \
    if (lane == 63) {                                                          \
      int tb = 1 + 7 * g;                                                      \
      _Pragma("unroll") for (int j = 0; j < (NS); ++j) {                       \
        int row = tb + j - 2;                                                  \
        if (row >= 0) partial[row * NW + wid] = sqv[j];                        \
      }                                                                        \
    }                                                                          \
  }

#define ESRNN_GROUP(QB, QP)                                                    \
  {                                                                            \
    PREFETCH(QP, g + 2)                                                        \
    ESRNN_GROUP_N(QB, 7)                                                       \
    ++g;                                                                       \
  }

__global__ __launch_bounds__(64) void esrnn_main(
    const float* __restrict__ train,        // (720, B)
    const float* __restrict__ lev_sms,      // (B,)
    const float* __restrict__ seas_sms,     // (B,)
    const float* __restrict__ init_seas_in, // (B, 7)
    float* __restrict__ levs_out,           // (720, B)
    float* __restrict__ seas_out,           // (727, B)
    float* __restrict__ partial)            // (718, NW) per-wave partials
{
  int b = blockIdx.x * 64 + threadIdx.x;
  bool valid = (b < B_DIM);
  int bc = valid ? b : (B_DIM - 1);
  int lane = threadIdx.x;
  int wid = blockIdx.x;

  float lsm = 1.0f / (1.0f + __expf(-lev_sms[bc]));
  float ssm = 1.0f / (1.0f + __expf(-seas_sms[bc]));
  float olm = 1.0f - lsm;
  float osm = 1.0f - ssm;

  float is[7];
#pragma unroll
  for (int j = 0; j < 7; ++j) is[j] = __expf(init_seas_in[bc * 7 + j]);

  float seas0 = is[0];
  float x0 = train[bc];
  float lev = __fdividef(x0, seas0);

  if (valid) {
    levs_out[b] = lev;
#pragma unroll
    for (int j = 0; j < 7; ++j) seas_out[j * B_DIM + b] = is[j];
    seas_out[7 * B_DIM + b] = seas0;
  }

  float buf[7];
#pragma unroll
  for (int j = 0; j < 6; ++j) buf[j] = is[j + 1];
  buf[6] = seas0;

  float llev = __log2f(lev);  // log2 units throughout; scaled by ln2^2 later
  float pld = 0.0f;

  // saddr-form store bases + shared per-lane byte offset.
  char* lbase = (char*)levs_out + (size_t)B_DIM * 4;      // row t=1
  char* sbase = (char*)seas_out + (size_t)8 * B_DIM * 4;  // row t+7=8
  unsigned int boff = (unsigned int)b * 4u;

  float xa[7], xb[7], xc[7];
  int g = 0;
  PREFETCH(xa, 0)
  PREFETCH(xb, 1)

  // 102 groups = 34 x 3-phase buffer rotation, prefetching 2 groups ahead.
  for (int k = 0; k < 34; ++k) {
    ESRNN_GROUP(xa, xc)
    ESRNN_GROUP(xb, xa)
    ESRNN_GROUP(xc, xb)
  }

  // tail: t = 715..719 in xa (group 102), buf pos 0..4
  ESRNN_GROUP_N(xa, 5)
}

__global__ __launch_bounds__(64) void esrnn_reduce2(
    const float* __restrict__ partial, float* __restrict__ msld) {
  int row = blockIdx.x;  // 0..717
  int lane = threadIdx.x;
  float s = 0.0f;
  for (int i = lane; i < NW; i += 64) s += partial[row * NW + i];
  float tot = dpp_sum64(s);
  if (lane == 63) msld[row] = tot * (LN2_SQ / (float)B_DIM);
}

extern "C" void kernel_launch(void* const* d_in, const int* in_sizes, int n_in,
                              void* d_out, int out_size, void* d_ws,
                              size_t ws_size, hipStream_t stream) {
  const float* train = (const float*)d_in[0];
  const float* lev_sms = (const float*)d_in[1];
  const float* seas_sms = (const float*)d_in[2];
  const float* init_seas = (const float*)d_in[3];

  float* out = (float*)d_out;
  float* levs = out;
  float* seas = out + OFF_SEAS;
  float* msld = out + OFF_MSLD;
  float* partial = (float*)d_ws;  // 718*782*4 ~= 2.25 MB

  esrnn_main<<<NBLK, 64, 0, stream>>>(train, lev_sms, seas_sms, init_seas,
                                      levs, seas, partial);
  esrnn_reduce2<<<N_MSLD, 64, 0, stream>>>(partial, msld);
}